// Round 13
// baseline (135.431 us; speedup 1.0000x reference)
//
#include <hip/hip_runtime.h>
#include <math.h>

#define BS 8
#define SEQ 1024
#define DIM 1024
#define FF 4096
#define NE 8
#define NSLOT 16
#define MAXM 8
#define NCHUNK 64

#define KS_UG 4
#define KC_UG (DIM / KS_UG)   // 256 floats = 64 f4 per k-chunk
#define KS_DN 16
#define KC_DN (FF / KS_DN)    // 256 floats = 64 f4 per k-chunk

// ws float offsets (identical to R12, which fit)
#define WS_LPART 0                               // 4096
#define WS_SELW  (WS_LPART + BS*NCHUNK*NE)       // 16
#define WS_SELE  (WS_SELW + NSLOT)               // 16 (ints)
#define WS_ACT   (WS_SELE + NSLOT)               // [NSLOT][FF] = 65536
#define WS_UPP   (WS_ACT + NSLOT*FF)             // [KS_UG][NSLOT][FF] = 262144
#define WS_GTP   (WS_UPP + KS_UG*NSLOT*FF)       // 262144
#define WS_YP    WS_UPP                          // alias: [KS_DN][NSLOT][DIM] = 262144
#define WS_Y     (WS_GTP + KS_UG*NSLOT*FF)       // 16384

__device__ __forceinline__ float dot4(float4 a, float4 b) {
    return a.x*b.x + a.y*b.y + a.z*b.z + a.w*b.w;
}

// ---- 1. h-chunk sum fused with router dot ----
__global__ __launch_bounds__(256) void klogit(const float4* __restrict__ h4,
                                              const float4* __restrict__ rw4,
                                              float* __restrict__ lpart) {
    const int c = blockIdx.x, b = blockIdx.y, t = threadIdx.x;
    const float4* p = h4 + ((size_t)b * SEQ + (size_t)c * 16) * (DIM/4) + t;
    float4 s = make_float4(0.f, 0.f, 0.f, 0.f);
    #pragma unroll
    for (int i = 0; i < 16; ++i) {
        float4 v = p[(size_t)i * (DIM/4)];
        s.x += v.x; s.y += v.y; s.z += v.z; s.w += v.w;
    }
    float pd[NE];
    #pragma unroll
    for (int e = 0; e < NE; ++e) pd[e] = dot4(s, rw4[(size_t)e * (DIM/4) + t]);
    #pragma unroll
    for (int o = 32; o; o >>= 1) {
        #pragma unroll
        for (int e = 0; e < NE; ++e) pd[e] += __shfl_xor(pd[e], o);
    }
    __shared__ float red[4][NE];
    const int wave = t >> 6, lane = t & 63;
    if (lane == 0) {
        #pragma unroll
        for (int e = 0; e < NE; ++e) red[wave][e] = pd[e];
    }
    __syncthreads();
    if (t < NE)
        lpart[(size_t)(b * NCHUNK + c) * NE + t] =
            red[0][t] + red[1][t] + red[2][t] + red[3][t];
}

// ---- 2. final logits + softmax + top2 ----
__global__ void krouter2(const float* __restrict__ lpart,
                         float* __restrict__ out_logits,
                         float* __restrict__ selw, int* __restrict__ sele) {
    const int t = threadIdx.x;  // 64
    __shared__ float lg[BS * NE];
    if (t < BS * NE) {
        const int b = t >> 3, e = t & 7;
        float s = 0.f;
        for (int c = 0; c < NCHUNK; ++c) s += lpart[(size_t)(b * NCHUNK + c) * NE + e];
        s *= (1.0f / (float)SEQ);
        lg[b * NE + e] = s;
        out_logits[b * NE + e] = s;
    }
    __syncthreads();
    if (t < BS) {
        float l[NE]; float mx = -1e30f;
        #pragma unroll
        for (int e = 0; e < NE; ++e) { l[e] = lg[t * NE + e]; mx = fmaxf(mx, l[e]); }
        float sum = 0.f;
        #pragma unroll
        for (int e = 0; e < NE; ++e) { l[e] = expf(l[e] - mx); sum += l[e]; }
        const float invs = 1.f / sum;
        float v1 = -1.f, v2 = -1.f; int e1 = -1, e2 = -1;
        #pragma unroll
        for (int e = 0; e < NE; ++e) {
            float pe = l[e] * invs;
            if (pe > v1)      { v2 = v1; e2 = e1; v1 = pe; e1 = e; }
            else if (pe > v2) { v2 = pe; e2 = e; }
        }
        selw[t * 2 + 0] = v1; sele[t * 2 + 0] = e1;
        selw[t * 2 + 1] = v2; sele[t * 2 + 1] = e2;
    }
}

__device__ __forceinline__ int build_slots(const int* __restrict__ sele, int e, int* slot) {
    unsigned mask = 0;
    #pragma unroll
    for (int s = 0; s < NSLOT; ++s) mask |= (sele[s] == e) ? (1u << s) : 0u;
    const int m = __popc(mask);
    unsigned mm = mask;
    #pragma unroll
    for (int ti = 0; ti < MAXM; ++ti) { slot[ti] = __ffs(mm) - 1; mm &= mm - 1; }
    return m;
}

__device__ __forceinline__ void slots_to_lds(const int* __restrict__ sele, int e,
                                             int t, int* sslot) {
    if (t < MAXM) {
        unsigned mask = 0;
        #pragma unroll
        for (int s = 0; s < NSLOT; ++s) mask |= (sele[s] == e) ? (1u << s) : 0u;
        unsigned mm = mask; int sl = -1;
        for (int k = 0; k <= t; ++k) { sl = __ffs(mm) - 1; mm &= mm - 1; }
        sslot[t] = sl;
    }
}

// ======== GEMV core: lane-owns-row, 16xf4 (256B = 2 full lines) bursts ========
// 4 iterations x 16 back-to-back dwordx4 per lane -> 16KB/wave in flight
// during each load phase. Single W buffer (64 VGPR), unroll-1 outer loop
// (R12-proven spill-free recipe), broadcast LDS x reads, zero shuffles.
__device__ __forceinline__ void gemv_lane16(const float4* __restrict__ wp,
                                            const float4* __restrict__ xs4,
                                            float* acc) {
    #pragma unroll 1
    for (int it = 0; it < 4; ++it) {
        float4 W[16];
        #pragma unroll
        for (int i = 0; i < 16; ++i) W[i] = wp[it * 16 + i];
        const float4* xb = xs4 + it * 16;
        #pragma unroll
        for (int i = 0; i < 16; ++i) {
            #pragma unroll
            for (int ti = 0; ti < MAXM; ++ti)
                acc[ti] += dot4(W[i], xb[ti * 64 + i]);
        }
    }
}

// ---- 3. up/gate partials: grid z = (mat, ks), 256 rows/block ----
__global__ __launch_bounds__(256) void kswiglu(const float* __restrict__ h,
                                               const float* __restrict__ w1,
                                               const float* __restrict__ w3,
                                               const int* __restrict__ sele,
                                               float* __restrict__ upp,
                                               float* __restrict__ gtp) {
    __shared__ float xs[MAXM * KC_UG];   // 8 KB
    __shared__ int sslot[MAXM];
    const int tile = blockIdx.x, e = blockIdx.y, t = threadIdx.x;
    const int mat = blockIdx.z & 1, ks = blockIdx.z >> 1;
    int slot[MAXM];
    const int m = build_slots(sele, e, slot);
    if (m == 0) return;
    slots_to_lds(sele, e, t, sslot);
    __syncthreads();
    {   // stage x chunks (zero-fill unused): 512 f4, 2 per thread
        float4* xsw = (float4*)xs;
        const float4* h4 = (const float4*)h;
        #pragma unroll
        for (int q = 0; q < 2; ++q) {
            const int idx = t + q * 256;
            const int ti = idx >> 6, j = idx & 63;
            const int s = sslot[ti];
            float4 v = make_float4(0.f, 0.f, 0.f, 0.f);
            if (ti < m)
                v = h4[((size_t)((s >> 1) * SEQ + (s & 1))) * (DIM/4) + ks * 64 + j];
            xsw[idx] = v;
        }
    }
    __syncthreads();
    const int wave = t >> 6, lane = t & 63;
    const int row = tile * 256 + wave * 64 + lane;       // lane-owned output row
    const float4* wp = (const float4*)(mat ? w3 : w1)
                       + ((size_t)e * FF + row) * (DIM/4) + ks * 64;
    float acc[MAXM];
    #pragma unroll
    for (int ti = 0; ti < MAXM; ++ti) acc[ti] = 0.f;
    gemv_lane16(wp, (const float4*)xs, acc);
    float* outp = (mat ? gtp : upp) + (size_t)ks * NSLOT * FF;
    #pragma unroll
    for (int ti = 0; ti < MAXM; ++ti)
        if (ti < m) outp[(size_t)slot[ti] * FF + row] = acc[ti];
}

// ---- 4. combine up/gate partials + silu -> act ----
__global__ __launch_bounds__(256) void kact(const float* __restrict__ upp,
                                            const float* __restrict__ gtp,
                                            float* __restrict__ act) {
    const int r = blockIdx.x * 256 + threadIdx.x, s = blockIdx.y;
    float u = 0.f, g = 0.f;
    #pragma unroll
    for (int ks = 0; ks < KS_UG; ++ks) {
        u += upp[((size_t)ks * NSLOT + s) * FF + r];
        g += gtp[((size_t)ks * NSLOT + s) * FF + r];
    }
    act[(size_t)s * FF + r] = (u / (1.f + expf(-u))) * g;
}

// ---- 5. down partials: grid z = ks, 256 rows/block ----
__global__ __launch_bounds__(256) void kdown(const float* __restrict__ w2,
                                             const float* __restrict__ act,
                                             const int* __restrict__ sele,
                                             float* __restrict__ yp) {
    __shared__ float xs[MAXM * KC_DN];   // 8 KB
    __shared__ int sslot[MAXM];
    const int tile = blockIdx.x, e = blockIdx.y, ks = blockIdx.z, t = threadIdx.x;
    int slot[MAXM];
    const int m = build_slots(sele, e, slot);
    if (m == 0) return;
    slots_to_lds(sele, e, t, sslot);
    __syncthreads();
    {   // stage act chunks (zero-fill unused)
        float4* xsw = (float4*)xs;
        const float4* a4 = (const float4*)act;
        #pragma unroll
        for (int q = 0; q < 2; ++q) {
            const int idx = t + q * 256;
            const int ti = idx >> 6, j = idx & 63;
            const int s = sslot[ti];
            float4 v = make_float4(0.f, 0.f, 0.f, 0.f);
            if (ti < m) v = a4[(size_t)s * (FF/4) + ks * 64 + j];
            xsw[idx] = v;
        }
    }
    __syncthreads();
    const int wave = t >> 6, lane = t & 63;
    const int row = tile * 256 + wave * 64 + lane;       // output row in DIM
    const float4* wp = (const float4*)w2
                       + ((size_t)e * DIM + row) * (FF/4) + ks * 64;
    float acc[MAXM];
    #pragma unroll
    for (int ti = 0; ti < MAXM; ++ti) acc[ti] = 0.f;
    gemv_lane16(wp, (const float4*)xs, acc);
    float* outp = yp + (size_t)ks * NSLOT * DIM;
    #pragma unroll
    for (int ti = 0; ti < MAXM; ++ti)
        if (ti < m) outp[(size_t)slot[ti] * DIM + row] = acc[ti];
}

// ---- 6. combine down partials x selw -> y ----
__global__ __launch_bounds__(256) void kcomby(const float* __restrict__ yp,
                                              const float* __restrict__ selw,
                                              float* __restrict__ y) {
    const int r = blockIdx.x * 256 + threadIdx.x, s = blockIdx.y;
    float v = 0.f;
    #pragma unroll
    for (int ks = 0; ks < KS_DN; ++ks)
        v += yp[((size_t)ks * NSLOT + s) * DIM + r];
    y[(size_t)s * DIM + r] = selw[s] * v;
}

// ---- 7. combine two selections per batch, broadcast across L ----
__global__ __launch_bounds__(256) void kbcast(const float4* __restrict__ y4,
                                              float4* __restrict__ out4) {
    const int b = blockIdx.y, lg = blockIdx.x, t = threadIdx.x;
    float4 y0 = y4[(size_t)(2 * b) * (DIM/4) + t];
    float4 y1 = y4[(size_t)(2 * b + 1) * (DIM/4) + t];
    float4 c = make_float4(y0.x + y1.x, y0.y + y1.y, y0.z + y1.z, y0.w + y1.w);
    size_t base = ((size_t)b * SEQ + (size_t)lg * 8) * (DIM/4) + t;
    #pragma unroll
    for (int i = 0; i < 8; ++i) out4[base + (size_t)i * (DIM/4)] = c;
}

extern "C" void kernel_launch(void* const* d_in, const int* in_sizes, int n_in,
                              void* d_out, int out_size, void* d_ws, size_t ws_size,
                              hipStream_t stream) {
    const float* h  = (const float*)d_in[0];
    const float* rw = (const float*)d_in[1];
    const float* w1 = (const float*)d_in[2];
    const float* w2 = (const float*)d_in[3];
    const float* w3 = (const float*)d_in[4];
    float* out = (float*)d_out;
    float* ws  = (float*)d_ws;

    float* lpart = ws + WS_LPART;
    float* selw  = ws + WS_SELW;
    int*   sele  = (int*)(ws + WS_SELE);
    float* act   = ws + WS_ACT;
    float* upp   = ws + WS_UPP;
    float* gtp   = ws + WS_GTP;
    float* yp    = ws + WS_YP;
    float* y     = ws + WS_Y;
    float* out_logits = out + (size_t)BS * SEQ * DIM;

    klogit  <<<dim3(NCHUNK, BS), 256, 0, stream>>>((const float4*)h, (const float4*)rw, lpart);
    krouter2<<<1, 64, 0, stream>>>(lpart, out_logits, selw, sele);
    kswiglu <<<dim3(FF / 256, NE, 2 * KS_UG), 256, 0, stream>>>(h, w1, w3, sele, upp, gtp);
    kact    <<<dim3(FF / 256, NSLOT), 256, 0, stream>>>(upp, gtp, act);
    kdown   <<<dim3(DIM / 256, NE, KS_DN), 256, 0, stream>>>(w2, act, sele, yp);
    kcomby  <<<dim3(DIM / 256, NSLOT), 256, 0, stream>>>(yp, selw, y);
    kbcast  <<<dim3(SEQ / 8, BS), 256, 0, stream>>>((const float4*)y, (float4*)out);
}